// Round 5
// baseline (78.324 us; speedup 1.0000x reference)
//
#include <hip/hip_runtime.h>

#define BATCH 4
#define NPTS  4096
#define TPB   64            // 1 wave per block
#define PPT   4             // P points per thread (register-tiled)
#define PB    (TPB * PPT)   // 256 P points per block
#define QC    128           // Q points per LDS stage (2 KB LDS as float4)
#define ZMAX  32            // max q-chunk slices (pmin footprint 4 MB)

// m = min(m, a, b) in one instruction. Inputs are finite (random normals),
// so v_min3 NaN semantics vs fminf are irrelevant; guarantees 0.5 min-ops
// per distance and a short dependency chain.
__device__ __forceinline__ void min3(float& m, float a, float b) {
    asm("v_min3_f32 %0, %0, %1, %2" : "+v"(m) : "v"(a), "v"(b));
}

// One launch covers both directions: blockIdx.y = dir*BATCH + b.
// Each thread holds PPT P points in registers; Q is consumed from LDS via
// wave-uniform broadcast ds_read_b128 (conflict-free), one per Q point,
// amortized over PPT distances. Per distance: 3 v_sub + 2 v_add (|.| input
// modifiers) + 0.5 v_min3 = 5.5 VALU lane-ops.
// Each block covers zsteps * QC consecutive Q points (runtime zsteps so the
// pmin footprint adapts to ws_size); partial mins stored conflict-free.
__global__ __launch_bounds__(TPB) void chamfer_all(const float* __restrict__ X,
                                                   const float* __restrict__ Y,
                                                   float* __restrict__ pmin,
                                                   float* __restrict__ out,
                                                   int zsteps) {
    // out[0] is re-poisoned before every launch; zero it here. Stream order
    // guarantees this kernel completes before reduce_loss's atomicAdds.
    if (blockIdx.x == 0 && blockIdx.y == 0 && blockIdx.z == 0 && threadIdx.x == 0)
        out[0] = 0.0f;

    const int dir = blockIdx.y >> 2;
    const int b   = blockIdx.y & 3;
    const int z   = blockIdx.z;
    const float* __restrict__ P = dir ? Y : X;
    const float* __restrict__ Q = dir ? X : Y;

    // P points in registers (coalesced 12B/lane loads, outside the hot loop)
    float px[PPT], py[PPT], pz[PPT], m[PPT];
    const int i0 = blockIdx.x * PB + threadIdx.x;
    #pragma unroll
    for (int u = 0; u < PPT; ++u) {
        const float* Pp = P + ((size_t)b * NPTS + i0 + u * TPB) * 3;
        px[u] = Pp[0];
        py[u] = Pp[1];
        pz[u] = Pp[2];
        m[u]  = __builtin_inff();
    }

    __shared__ float4 sq[QC];
    const int q0 = z * zsteps * QC;

    for (int s = 0; s < zsteps; ++s) {
        __syncthreads();   // previous stage consumed (near-free for 1 wave)
        const float* __restrict__ Qb = Q + ((size_t)b * NPTS + q0 + s * QC) * 3;
        for (int k = threadIdx.x; k < QC; k += TPB)
            sq[k] = make_float4(Qb[3 * k], Qb[3 * k + 1], Qb[3 * k + 2], 0.0f);
        __syncthreads();

        #pragma unroll 4
        for (int j = 0; j < QC; j += 2) {
            const float4 qa = sq[j];       // broadcast ds_read_b128
            const float4 qb = sq[j + 1];
            #pragma unroll
            for (int u = 0; u < PPT; ++u) {
                float d0 = fabsf(px[u] - qa.x) + fabsf(py[u] - qa.y) + fabsf(pz[u] - qa.z);
                float d1 = fabsf(px[u] - qb.x) + fabsf(py[u] - qb.y) + fabsf(pz[u] - qb.z);
                min3(m[u], d0, d1);
            }
        }
    }

    float* dst = pmin + ((size_t)dir * gridDim.z + z) * (BATCH * NPTS) + b * NPTS + i0;
    #pragma unroll
    for (int u = 0; u < PPT; ++u) dst[u * TPB] = m[u];   // coalesced, no atomics
}

// pmin: [2][Z][BATCH*NPTS]. One slot per thread: min over Z (coalesced per z),
// then deterministic block sum; one atomicAdd per block into zeroed out[0].
__global__ __launch_bounds__(256) void reduce_loss(const float* __restrict__ pmin,
                                                   float* __restrict__ out, int Z) {
    const int half = BATCH * NPTS;                      // 16384 = 2^14
    const int s    = blockIdx.x * 256 + threadIdx.x;    // 0 .. 2*half-1
    const int dir  = s >> 14;
    const int idx  = s & (half - 1);

    const float* __restrict__ base = pmin + (size_t)dir * Z * half + idx;
    float v = base[0];
    for (int z = 1; z < Z; ++z) v = fminf(v, base[(size_t)z * half]);

    for (int off = 32; off > 0; off >>= 1) v += __shfl_down(v, off, 64);

    __shared__ float partial[4];
    if ((threadIdx.x & 63) == 0) partial[threadIdx.x >> 6] = v;
    __syncthreads();
    if (threadIdx.x == 0) {
        // mean(cham_x) + mean(cham_y) = (sum_x + sum_y) / (B*N)   (N == M)
        float t = (partial[0] + partial[1] + partial[2] + partial[3]) *
                  (1.0f / (float)half);
        atomicAdd(out, t);
    }
}

extern "C" void kernel_launch(void* const* d_in, const int* in_sizes, int n_in,
                              void* d_out, int out_size, void* d_ws, size_t ws_size,
                              hipStream_t stream) {
    const float* X = (const float*)d_in[0];
    const float* Y = (const float*)d_in[1];
    float* out = (float*)d_out;
    float* pmin = (float*)d_ws;

    // Largest Z whose pmin footprint (2 * Z * BATCH*NPTS floats) fits ws.
    int Z = ZMAX;
    while (Z > 1 && (size_t)2 * Z * BATCH * NPTS * sizeof(float) > ws_size) Z >>= 1;
    const int zsteps = ZMAX / Z;            // Q points per block = zsteps * QC

    dim3 grid(NPTS / PB, 2 * BATCH, Z);     // Z=32: 16 x 8 x 32 = 4096 blocks
    chamfer_all<<<grid, TPB, 0, stream>>>(X, Y, pmin, out, zsteps);

    reduce_loss<<<(2 * BATCH * NPTS) / 256, 256, 0, stream>>>(pmin, out, Z);
}